// Round 6
// baseline (235.849 us; speedup 1.0000x reference)
//
#include <hip/hip_runtime.h>
#include <hip/hip_bf16.h>
#include <math.h>

#define N_SLOTS 4096
#define DIM 256
#define HEADS 4
#define RANK 32
#define TOPK 32
#define QK 128  // HEADS*RANK

typedef __attribute__((ext_vector_type(8))) short short8;   // 8 bf16 = 4 VGPR
typedef __attribute__((ext_vector_type(4))) float f32x4;

// ---- block-wide sum over 256 threads (4 waves) ----
__device__ __forceinline__ float block_sum256(float v, float* red) {
#pragma unroll
  for (int o = 32; o > 0; o >>= 1) v += __shfl_xor(v, o);
  int lane = threadIdx.x & 63, wid = threadIdx.x >> 6;
  if (lane == 0) red[wid] = v;
  __syncthreads();
  v = red[0] + red[1] + red[2] + red[3];
  __syncthreads();
  return v;
}

// ---- Kernel A: LayerNorm + unit-normalize rows of init_val -> val0 [N,D] ----
__global__ __launch_bounds__(256) void ln_unit_kernel(
    const float* __restrict__ x, const float* __restrict__ g,
    const float* __restrict__ b, float* __restrict__ val0) {
  __shared__ float red[4];
  int n = blockIdx.x, t = threadIdx.x;
  float v = x[n * DIM + t];
  float mean = block_sum256(v, red) * (1.0f / DIM);
  float d = v - mean;
  float var = block_sum256(d * d, red) * (1.0f / DIM);
  float y = d * rsqrtf(var + 1e-5f) * g[t] + b[t];
  float ss = block_sum256(y * y, red);
  y = y / fmaxf(sqrtf(ss), 1e-6f);
  val0[n * DIM + t] = y;
}

// ---- Kernel B: q/k projections, 8 rows/block (weights read amortized 8x),
//      + bf16 hi/lo split for MFMA operands ----
#define QR 8
__global__ __launch_bounds__(128) void qk2_kernel(
    const float* __restrict__ val0, const float* __restrict__ Wq,
    const float* __restrict__ Wk, __hip_bfloat16* __restrict__ qh,
    __hip_bfloat16* __restrict__ ql, __hip_bfloat16* __restrict__ kh,
    __hip_bfloat16* __restrict__ kl) {
  __shared__ float v[QR][DIM];  // 8 KB
  int t = threadIdx.x;  // 128 threads
  int n0 = blockIdx.x * QR;
#pragma unroll
  for (int j = 0; j < 2 * QR; ++j) {
    int f = j * 128 + t;
    int row = f >> 8, d = f & 255;
    v[row][d] = val0[(size_t)(n0 + row) * DIM + d];
  }
  __syncthreads();
  int h = t >> 5, r = t & 31;
  const float* wqp = Wq + (size_t)h * DIM * RANK + r;
  const float* wkp = Wk + (size_t)h * DIM * RANK + r;
  float aq[QR], ak[QR];
#pragma unroll
  for (int i = 0; i < QR; ++i) { aq[i] = 0.f; ak[i] = 0.f; }
  for (int d4 = 0; d4 < DIM; d4 += 4) {
    float wq[4], wk[4];
#pragma unroll
    for (int e = 0; e < 4; ++e) {
      wq[e] = wqp[(d4 + e) * RANK];
      wk[e] = wkp[(d4 + e) * RANK];
    }
#pragma unroll
    for (int row = 0; row < QR; ++row) {
      float4 vv = *(const float4*)&v[row][d4];
      aq[row] = fmaf(vv.x, wq[0], aq[row]); ak[row] = fmaf(vv.x, wk[0], ak[row]);
      aq[row] = fmaf(vv.y, wq[1], aq[row]); ak[row] = fmaf(vv.y, wk[1], ak[row]);
      aq[row] = fmaf(vv.z, wq[2], aq[row]); ak[row] = fmaf(vv.z, wk[2], ak[row]);
      aq[row] = fmaf(vv.w, wq[3], aq[row]); ak[row] = fmaf(vv.w, wk[3], ak[row]);
    }
  }
#pragma unroll
  for (int row = 0; row < QR; ++row) {
    size_t o = (size_t)(n0 + row) * QK + t;
    __hip_bfloat16 h1 = __float2bfloat16(aq[row]);
    qh[o] = h1;
    ql[o] = __float2bfloat16(aq[row] - __bfloat162float(h1));
    __hip_bfloat16 h2 = __float2bfloat16(ak[row]);
    kh[o] = h2;
    kl[o] = __float2bfloat16(ak[row] - __bfloat162float(h2));
  }
}

// ---- Kernel C: scores via 16x16x32 bf16 MFMA (hh+hl+lh split), TILED S out.
// S layout: tile (ry,cx) of 64x64 stored contiguously (16 KB) at
// ((ry*64)+cx)*4096. LDS-staged store -> 1KB-contiguous wave stores. ----
#define TPAD 68
__global__ __launch_bounds__(256) void scores_mfma_kernel(
    const __hip_bfloat16* __restrict__ qh, const __hip_bfloat16* __restrict__ ql,
    const __hip_bfloat16* __restrict__ kh, const __hip_bfloat16* __restrict__ kl,
    float* __restrict__ S, int row0) {
  __shared__ float tile[64 * TPAD];
  int tid = threadIdx.x;
  int w = tid >> 6, l = tid & 63;
  int r = l & 15, g = l >> 4;
  int arow = row0 + blockIdx.y * 64 + w * 16 + r;
  int bcol = blockIdx.x * 64;

  const __hip_bfloat16* qhp = qh + (size_t)arow * QK + g * 8;
  const __hip_bfloat16* qlp = ql + (size_t)arow * QK + g * 8;
  short8 ah[4], al[4];
#pragma unroll
  for (int kc = 0; kc < 4; ++kc) {
    ah[kc] = *(const short8*)(qhp + kc * 32);
    al[kc] = *(const short8*)(qlp + kc * 32);
  }
  f32x4 acc[4];
#pragma unroll
  for (int c = 0; c < 4; ++c) acc[c] = (f32x4){0.f, 0.f, 0.f, 0.f};
#pragma unroll
  for (int c = 0; c < 4; ++c) {
    const __hip_bfloat16* khp = kh + (size_t)(bcol + c * 16 + r) * QK + g * 8;
    const __hip_bfloat16* klp = kl + (size_t)(bcol + c * 16 + r) * QK + g * 8;
#pragma unroll
    for (int kc = 0; kc < 4; ++kc) {
      short8 bh = *(const short8*)(khp + kc * 32);
      short8 bl = *(const short8*)(klp + kc * 32);
      acc[c] = __builtin_amdgcn_mfma_f32_16x16x32_bf16(ah[kc], bh, acc[c], 0, 0, 0);
      acc[c] = __builtin_amdgcn_mfma_f32_16x16x32_bf16(ah[kc], bl, acc[c], 0, 0, 0);
      acc[c] = __builtin_amdgcn_mfma_f32_16x16x32_bf16(al[kc], bh, acc[c], 0, 0, 0);
    }
  }
  // C-frag (col=r, row=g*4+reg) -> LDS tile (2-way bank aliasing only, free)
#pragma unroll
  for (int c = 0; c < 4; ++c)
#pragma unroll
    for (int reg = 0; reg < 4; ++reg)
      tile[(w * 16 + g * 4 + reg) * TPAD + c * 16 + r] = acc[c][reg];
  __syncthreads();
  // stream 16 KB tile contiguously: each wave stores 1 KB runs
  float* Stile = S + ((size_t)blockIdx.y * 64 + blockIdx.x) * 4096;
#pragma unroll
  for (int p = 0; p < 4; ++p) {
    int f = p * 256 + tid;          // float4 index 0..1023
    int row = f >> 4, f4 = f & 15;
    float4 val = *(const float4*)&tile[row * TPAD + f4 * 4];
    *(float4*)(Stile + (size_t)f * 4) = val;
  }
}

// ---- Kernel D: per-row exact top-32 via 3-round radix select (11/11/10
//      bits, 4-way wave-privatized 2048-bin histograms), signed softmax,
//      gather-aggregate, unit-normalize. Reads tiled S. ----
__global__ __launch_bounds__(256) void topk_agg_kernel(
    const float* __restrict__ S, const float* __restrict__ val0,
    float* __restrict__ out, int row0, int B) {
  __shared__ int hist[4 * 2048];  // 32 KB, copy per wave
  __shared__ int s_wtot[4];
  __shared__ int s_piv[2];
  __shared__ int s_selidx[TOPK];
  __shared__ float s_selval[TOPK];
  __shared__ int s_tiei[64];
  __shared__ float s_tiev[64];
  __shared__ int s_cnt[2];
  __shared__ float s_w[TOPK];
  __shared__ float red[4];

  int t = threadIdx.x, lane = t & 63, wid = t >> 6;
  int n = row0 + blockIdx.x;
  int rt = blockIdx.x >> 6, rl = blockIdx.x & 63;
  const float* Sbase = S + (size_t)rt * 64 * N_SLOTS + (size_t)rl * 64;

  float v[16];
  unsigned key[16];
#pragma unroll
  for (int it = 0; it < 4; ++it) {
    int idx4 = it * 256 + t;
    int ct = idx4 >> 4, f4 = idx4 & 15;
    float4 f = *(const float4*)(Sbase + (size_t)ct * 4096 + f4 * 4);
    v[it * 4 + 0] = f.x; v[it * 4 + 1] = f.y;
    v[it * 4 + 2] = f.z; v[it * 4 + 3] = f.w;
  }
#pragma unroll
  for (int e = 0; e < 16; ++e) key[e] = __float_as_uint(fabsf(v[e]));

  // ---- radix select: exact threshold key T of rank TOPK ----
  unsigned prefix = 0u, pmask = 0u;
  int Kr = TOPK;
  const int SH[3] = {21, 10, 0};
  const unsigned BM[3] = {2047u, 2047u, 1023u};
#pragma unroll
  for (int rnd = 0; rnd < 3; ++rnd) {
    int shift = SH[rnd];
    unsigned bmask = BM[rnd];
#pragma unroll
    for (int cp = 0; cp < 4; ++cp) {
      *(int4*)&hist[cp * 2048 + t * 8] = (int4){0, 0, 0, 0};
      *(int4*)&hist[cp * 2048 + t * 8 + 4] = (int4){0, 0, 0, 0};
    }
    __syncthreads();
#pragma unroll
    for (int e = 0; e < 16; ++e)
      if ((key[e] & pmask) == prefix)
        atomicAdd(&hist[wid * 2048 + ((key[e] >> shift) & bmask)], 1);
    __syncthreads();
    int hl[8], sl[8];
    {
      int4 a0 = *(const int4*)&hist[0 * 2048 + t * 8];
      int4 a1 = *(const int4*)&hist[1 * 2048 + t * 8];
      int4 a2 = *(const int4*)&hist[2 * 2048 + t * 8];
      int4 a3 = *(const int4*)&hist[3 * 2048 + t * 8];
      int4 b0 = *(const int4*)&hist[0 * 2048 + t * 8 + 4];
      int4 b1 = *(const int4*)&hist[1 * 2048 + t * 8 + 4];
      int4 b2 = *(const int4*)&hist[2 * 2048 + t * 8 + 4];
      int4 b3 = *(const int4*)&hist[3 * 2048 + t * 8 + 4];
      hl[0] = a0.x + a1.x + a2.x + a3.x; hl[1] = a0.y + a1.y + a2.y + a3.y;
      hl[2] = a0.z + a1.z + a2.z + a3.z; hl[3] = a0.w + a1.w + a2.w + a3.w;
      hl[4] = b0.x + b1.x + b2.x + b3.x; hl[5] = b0.y + b1.y + b2.y + b3.y;
      hl[6] = b0.z + b1.z + b2.z + b3.z; hl[7] = b0.w + b1.w + b2.w + b3.w;
    }
    int run = 0;
#pragma unroll
    for (int j = 7; j >= 0; --j) { run += hl[j]; sl[j] = run; }
    int ws = run;
#pragma unroll
    for (int o = 1; o < 64; o <<= 1) {
      int tmp = __shfl_down(ws, o);
      if (lane + o < 64) ws += tmp;
    }
    if (lane == 0) s_wtot[wid] = ws;
    __syncthreads();
    int above = ws - run;
    for (int ww = wid + 1; ww < 4; ++ww) above += s_wtot[ww];
#pragma unroll
    for (int j = 0; j < 8; ++j) {
      int suf = sl[j] + above;           // count with bin >= (t*8+j)
      if (suf >= Kr && suf - hl[j] < Kr) {
        s_piv[0] = t * 8 + j;
        s_piv[1] = suf - hl[j];          // count strictly greater
      }
    }
    __syncthreads();
    prefix |= ((unsigned)s_piv[0]) << shift;
    pmask |= bmask << shift;
    Kr -= s_piv[1];
    __syncthreads();
  }
  unsigned T = prefix;  // exact rank-TOPK |score| bit pattern

  // ---- compaction: all key>T, plus lowest-index ties at key==T ----
  if (t < 2) s_cnt[t] = 0;
  __syncthreads();
#pragma unroll
  for (int e = 0; e < 16; ++e) {
    int idx4 = (e >> 2) * 256 + t;
    int m = (idx4 >> 4) * 64 + (idx4 & 15) * 4 + (e & 3);  // global col
    if (key[e] > T) {
      int p = atomicAdd(&s_cnt[0], 1);
      s_selidx[p] = m;
      s_selval[p] = v[e];
    } else if (key[e] == T) {
      int p = atomicAdd(&s_cnt[1], 1);
      if (p < 64) { s_tiei[p] = m; s_tiev[p] = v[e]; }
    }
  }
  __syncthreads();
  int cnt_gt = s_cnt[0];
  int need = TOPK - cnt_gt;  // ties to take, lowest index first
  if (wid == 0) {
    int ce = min(s_cnt[1], 64);
    int cand = (lane < ce) ? s_tiei[lane] : 0x7fffffff;
    float cval = (lane < ce) ? s_tiev[lane] : 0.0f;
    for (int i = 0; i < need; ++i) {
      int mi = cand;
#pragma unroll
      for (int o = 32; o > 0; o >>= 1) mi = min(mi, __shfl_xor(mi, o));
      if (cand == mi) {
        s_selidx[cnt_gt + i] = cand;
        s_selval[cnt_gt + i] = cval;
        cand = 0x7fffffff;
      }
    }
    // ---- signed softmax over the selected 32 (one wave, width-32) ----
    float sv = (lane < TOPK) ? s_selval[lane] : 0.0f;
    float aa = fabsf(sv);
    float mx = aa;
#pragma unroll
    for (int o = 16; o > 0; o >>= 1) mx = fmaxf(mx, __shfl_xor(mx, o, 32));
    float e2 = expf(aa - mx);
    float sum = e2;
#pragma unroll
    for (int o = 16; o > 0; o >>= 1) sum += __shfl_xor(sum, o, 32);
    if (lane < TOPK) {
      float sgn = (sv > 0.f) ? 1.f : ((sv < 0.f) ? -1.f : 0.f);
      s_w[lane] = sgn * e2 / sum;
    }
  }
  __syncthreads();

  // ---- aggregate + residual + unit-normalize; replicate across batch ----
  float base = val0[n * DIM + t];
  float msg = 0.f;
#pragma unroll
  for (int kk = 0; kk < TOPK; ++kk)
    msg = fmaf(s_w[kk], val0[(size_t)s_selidx[kk] * DIM + t], msg);
  float o = base + msg;
  float ss = block_sum256(o * o, red);
  o *= 1.0f / fmaxf(sqrtf(ss), 1e-6f);
  for (int b = 0; b < B; ++b) out[((size_t)b * N_SLOTS + n) * DIM + t] = o;
}

extern "C" void kernel_launch(void* const* d_in, const int* in_sizes, int n_in,
                              void* d_out, int out_size, void* d_ws, size_t ws_size,
                              hipStream_t stream) {
  // inputs: 0 batch_size, 1 init_state (unused), 2 init_val, 3 ln_gamma,
  //         4 ln_beta, 5 Wq, 6 Wk
  const float* init_val = (const float*)d_in[2];
  const float* g = (const float*)d_in[3];
  const float* b = (const float*)d_in[4];
  const float* Wq = (const float*)d_in[5];
  const float* Wk = (const float*)d_in[6];
  float* out = (float*)d_out;
  int B = out_size / (N_SLOTS * DIM);  // = 4

  // workspace: val0 4MB | qh/ql/kh/kl 1MB each | S chunk @8MB (tiled layout)
  char* ws = (char*)d_ws;
  float* val0 = (float*)ws;
  __hip_bfloat16* qh = (__hip_bfloat16*)(ws + ((size_t)4 << 20));
  __hip_bfloat16* ql = (__hip_bfloat16*)(ws + ((size_t)5 << 20));
  __hip_bfloat16* kh = (__hip_bfloat16*)(ws + ((size_t)6 << 20));
  __hip_bfloat16* kl = (__hip_bfloat16*)(ws + ((size_t)7 << 20));
  float* S = (float*)(ws + ((size_t)8 << 20));
  size_t rem = ws_size > ((size_t)8 << 20) ? ws_size - ((size_t)8 << 20) : 0;
  int rows_chunk = (int)((rem / ((size_t)N_SLOTS * sizeof(float))) / 64) * 64;
  if (rows_chunk > N_SLOTS) rows_chunk = N_SLOTS;
  if (rows_chunk < 64) rows_chunk = 64;  // require ~9MB of ws minimum

  hipLaunchKernelGGL(ln_unit_kernel, dim3(N_SLOTS), dim3(DIM), 0, stream,
                     init_val, g, b, val0);
  hipLaunchKernelGGL(qk2_kernel, dim3(N_SLOTS / QR), dim3(QK), 0, stream,
                     val0, Wq, Wk, qh, ql, kh, kl);
  for (int start = 0; start < N_SLOTS; start += rows_chunk) {
    int rows = N_SLOTS - start;
    if (rows > rows_chunk) rows = rows_chunk;
    hipLaunchKernelGGL(scores_mfma_kernel, dim3(N_SLOTS / 64, rows / 64),
                       dim3(256), 0, stream, qh, ql, kh, kl, S, start);
    hipLaunchKernelGGL(topk_agg_kernel, dim3(rows), dim3(256), 0, stream,
                       S, val0, out, start, B);
  }
}

// Round 7
// 201.768 us; speedup vs baseline: 1.1689x; 1.1689x over previous
//
#include <hip/hip_runtime.h>
#include <hip/hip_bf16.h>
#include <math.h>

#define N_SLOTS 4096
#define DIM 256
#define HEADS 4
#define RANK 32
#define TOPK 32
#define QK 128  // HEADS*RANK

typedef __attribute__((ext_vector_type(8))) short short8;   // 8 bf16 = 4 VGPR
typedef __attribute__((ext_vector_type(4))) float f32x4;

// ---- block-wide sum over 256 threads (4 waves) ----
__device__ __forceinline__ float block_sum256(float v, float* red) {
#pragma unroll
  for (int o = 32; o > 0; o >>= 1) v += __shfl_xor(v, o);
  int lane = threadIdx.x & 63, wid = threadIdx.x >> 6;
  if (lane == 0) red[wid] = v;
  __syncthreads();
  v = red[0] + red[1] + red[2] + red[3];
  __syncthreads();
  return v;
}

// ---- Kernel A: LayerNorm + unit-normalize rows of init_val -> val0 [N,D] ----
__global__ __launch_bounds__(256) void ln_unit_kernel(
    const float* __restrict__ x, const float* __restrict__ g,
    const float* __restrict__ b, float* __restrict__ val0) {
  __shared__ float red[4];
  int n = blockIdx.x, t = threadIdx.x;
  float v = x[n * DIM + t];
  float mean = block_sum256(v, red) * (1.0f / DIM);
  float d = v - mean;
  float var = block_sum256(d * d, red) * (1.0f / DIM);
  float y = d * rsqrtf(var + 1e-5f) * g[t] + b[t];
  float ss = block_sum256(y * y, red);
  y = y / fmaxf(sqrtf(ss), 1e-6f);
  val0[n * DIM + t] = y;
}

// ---- Kernel B: q/k projections. 256 thr: half 0 computes q (reads Wq only),
//      half 1 computes k (reads Wk only); QR=4 rows/block -> 1024 blocks,
//      16 waves/CU. Unroll-8 scalar weight loads for ILP. bf16 hi/lo split. ----
#define QR 4
__global__ __launch_bounds__(256) void qk2_kernel(
    const float* __restrict__ val0, const float* __restrict__ Wq,
    const float* __restrict__ Wk, __hip_bfloat16* __restrict__ qh,
    __hip_bfloat16* __restrict__ ql, __hip_bfloat16* __restrict__ kh,
    __hip_bfloat16* __restrict__ kl) {
  __shared__ float vrow[QR][DIM];  // 4 KB
  int t = threadIdx.x;
  int n0 = blockIdx.x * QR;
#pragma unroll
  for (int j = 0; j < QR; ++j) {
    int idx = j * 256 + t;
    vrow[idx >> 8][idx & 255] = val0[(size_t)n0 * DIM + idx];
  }
  __syncthreads();
  int half = t >> 7, u = t & 127, h = u >> 5, r = u & 31;
  const float* wp = (half ? Wk : Wq) + (size_t)h * DIM * RANK + r;
  float acc[QR];
#pragma unroll
  for (int i = 0; i < QR; ++i) acc[i] = 0.f;
#pragma unroll 8
  for (int d = 0; d < DIM; ++d) {
    float w = wp[d * RANK];
#pragma unroll
    for (int i = 0; i < QR; ++i) acc[i] = fmaf(vrow[i][d], w, acc[i]);
  }
  __hip_bfloat16* oh = half ? kh : qh;
  __hip_bfloat16* ol = half ? kl : ql;
#pragma unroll
  for (int i = 0; i < QR; ++i) {
    size_t o = (size_t)(n0 + i) * QK + u;
    __hip_bfloat16 hi = __float2bfloat16(acc[i]);
    oh[o] = hi;
    ol[o] = __float2bfloat16(acc[i] - __bfloat162float(hi));
  }
}

// ---- Kernel C: scores via 16x16x32 bf16 MFMA (hh+hl+lh split).
// K-panel (64 cols of S = 64 rows of k) cooperatively staged in LDS in
// fragment order with XOR swizzle; q-frags in registers. Tiled S output
// via LDS bounce (16 KB contiguous per tile). ----
#define TPAD 68
__device__ __forceinline__ int swz(int i) { return i ^ ((i >> 4) & 7); }

__global__ __launch_bounds__(256) void scores_mfma_kernel(
    const __hip_bfloat16* __restrict__ qh, const __hip_bfloat16* __restrict__ ql,
    const __hip_bfloat16* __restrict__ kh, const __hip_bfloat16* __restrict__ kl,
    float* __restrict__ S, int row0) {
  __shared__ short8 kfrag[2048];     // [hl][kc][c][lane] 32 KB, swizzled
  __shared__ float tile[64 * TPAD];  // 17 KB bounce
  int tid = threadIdx.x;
  int w = tid >> 6, l = tid & 63;
  int r = l & 15, g = l >> 4;
  int bcol = blockIdx.x * 64;
  int arow = row0 + blockIdx.y * 64 + w * 16 + r;

  // q fragments -> registers (8 x 16B loads, issued together)
  const __hip_bfloat16* qhp = qh + (size_t)arow * QK + g * 8;
  const __hip_bfloat16* qlp = ql + (size_t)arow * QK + g * 8;
  short8 ah[4], al[4];
#pragma unroll
  for (int kc = 0; kc < 4; ++kc) {
    ah[kc] = *(const short8*)(qhp + kc * 32);
    al[kc] = *(const short8*)(qlp + kc * 32);
  }

  // stage k panel (rows bcol..bcol+63) into fragment-ordered LDS
  // chunk ci (16B): row = ci>>4, j = ci&15; frag idx = (j>>2)*256 +
  // (row>>4)*64 + (j&3)*16 + (row&15)
#pragma unroll
  for (int p = 0; p < 4; ++p) {
    int ci = p * 256 + tid;  // 0..1023
    int row = ci >> 4, j = ci & 15;
    int fi = ((j >> 2) << 8) + ((row >> 4) << 6) + ((j & 3) << 4) + (row & 15);
    const __hip_bfloat16* src = kh + (size_t)(bcol + row) * QK + j * 8;
    const __hip_bfloat16* srl = kl + (size_t)(bcol + row) * QK + j * 8;
    kfrag[swz(fi)] = *(const short8*)src;
    kfrag[swz(1024 + fi)] = *(const short8*)srl;
  }
  __syncthreads();

  f32x4 acc[4];
#pragma unroll
  for (int c = 0; c < 4; ++c) acc[c] = (f32x4){0.f, 0.f, 0.f, 0.f};
#pragma unroll
  for (int c = 0; c < 4; ++c) {
#pragma unroll
    for (int kc = 0; kc < 4; ++kc) {
      short8 bh = kfrag[swz(kc * 256 + c * 64 + l)];
      short8 bl = kfrag[swz(1024 + kc * 256 + c * 64 + l)];
      acc[c] = __builtin_amdgcn_mfma_f32_16x16x32_bf16(ah[kc], bh, acc[c], 0, 0, 0);
      acc[c] = __builtin_amdgcn_mfma_f32_16x16x32_bf16(ah[kc], bl, acc[c], 0, 0, 0);
      acc[c] = __builtin_amdgcn_mfma_f32_16x16x32_bf16(al[kc], bh, acc[c], 0, 0, 0);
    }
  }
  // C-frag (col=r, row=g*4+reg) -> bounce tile
#pragma unroll
  for (int c = 0; c < 4; ++c)
#pragma unroll
    for (int reg = 0; reg < 4; ++reg)
      tile[(w * 16 + g * 4 + reg) * TPAD + c * 16 + r] = acc[c][reg];
  __syncthreads();
  // stream 16 KB tile contiguously
  float* Stile = S + ((size_t)blockIdx.y * gridDim.x + blockIdx.x) * 4096;
#pragma unroll
  for (int p = 0; p < 4; ++p) {
    int f = p * 256 + tid;  // float4 index 0..1023
    int row = f >> 4, f4 = f & 15;
    float4 val = *(const float4*)&tile[row * TPAD + f4 * 4];
    *(float4*)(Stile + (size_t)f * 4) = val;
  }
}

// ---- Kernel D: per-row exact top-32 via 3-round radix select (11/11/10
//      bits, 4-way wave-privatized 2048-bin histograms), signed softmax,
//      gather-aggregate, unit-normalize. Reads tiled S. ----
__global__ __launch_bounds__(256) void topk_agg_kernel(
    const float* __restrict__ S, const float* __restrict__ val0,
    float* __restrict__ out, int row0, int B) {
  __shared__ int hist[4 * 2048];  // 32 KB, copy per wave
  __shared__ int s_wtot[4];
  __shared__ int s_piv[2];
  __shared__ int s_selidx[TOPK];
  __shared__ float s_selval[TOPK];
  __shared__ int s_tiei[64];
  __shared__ float s_tiev[64];
  __shared__ int s_cnt[2];
  __shared__ float s_w[TOPK];
  __shared__ float red[4];

  int t = threadIdx.x, lane = t & 63, wid = t >> 6;
  int n = row0 + blockIdx.x;
  int rt = blockIdx.x >> 6, rl = blockIdx.x & 63;
  const float* Sbase = S + (size_t)rt * 64 * N_SLOTS + (size_t)rl * 64;

  float v[16];
  unsigned key[16];
#pragma unroll
  for (int it = 0; it < 4; ++it) {
    int idx4 = it * 256 + t;
    int ct = idx4 >> 4, f4 = idx4 & 15;
    float4 f = *(const float4*)(Sbase + (size_t)ct * 4096 + f4 * 4);
    v[it * 4 + 0] = f.x; v[it * 4 + 1] = f.y;
    v[it * 4 + 2] = f.z; v[it * 4 + 3] = f.w;
  }
#pragma unroll
  for (int e = 0; e < 16; ++e) key[e] = __float_as_uint(fabsf(v[e]));

  // ---- radix select: exact threshold key T of rank TOPK ----
  unsigned prefix = 0u, pmask = 0u;
  int Kr = TOPK;
  const int SH[3] = {21, 10, 0};
  const unsigned BM[3] = {2047u, 2047u, 1023u};
#pragma unroll
  for (int rnd = 0; rnd < 3; ++rnd) {
    int shift = SH[rnd];
    unsigned bmask = BM[rnd];
#pragma unroll
    for (int cp = 0; cp < 4; ++cp) {
      *(int4*)&hist[cp * 2048 + t * 8] = (int4){0, 0, 0, 0};
      *(int4*)&hist[cp * 2048 + t * 8 + 4] = (int4){0, 0, 0, 0};
    }
    __syncthreads();
#pragma unroll
    for (int e = 0; e < 16; ++e)
      if ((key[e] & pmask) == prefix)
        atomicAdd(&hist[wid * 2048 + ((key[e] >> shift) & bmask)], 1);
    __syncthreads();
    int hl[8], sl[8];
    {
      int4 a0 = *(const int4*)&hist[0 * 2048 + t * 8];
      int4 a1 = *(const int4*)&hist[1 * 2048 + t * 8];
      int4 a2 = *(const int4*)&hist[2 * 2048 + t * 8];
      int4 a3 = *(const int4*)&hist[3 * 2048 + t * 8];
      int4 b0 = *(const int4*)&hist[0 * 2048 + t * 8 + 4];
      int4 b1 = *(const int4*)&hist[1 * 2048 + t * 8 + 4];
      int4 b2 = *(const int4*)&hist[2 * 2048 + t * 8 + 4];
      int4 b3 = *(const int4*)&hist[3 * 2048 + t * 8 + 4];
      hl[0] = a0.x + a1.x + a2.x + a3.x; hl[1] = a0.y + a1.y + a2.y + a3.y;
      hl[2] = a0.z + a1.z + a2.z + a3.z; hl[3] = a0.w + a1.w + a2.w + a3.w;
      hl[4] = b0.x + b1.x + b2.x + b3.x; hl[5] = b0.y + b1.y + b2.y + b3.y;
      hl[6] = b0.z + b1.z + b2.z + b3.z; hl[7] = b0.w + b1.w + b2.w + b3.w;
    }
    int run = 0;
#pragma unroll
    for (int j = 7; j >= 0; --j) { run += hl[j]; sl[j] = run; }
    int ws = run;
#pragma unroll
    for (int o = 1; o < 64; o <<= 1) {
      int tmp = __shfl_down(ws, o);
      if (lane + o < 64) ws += tmp;
    }
    if (lane == 0) s_wtot[wid] = ws;
    __syncthreads();
    int above = ws - run;
    for (int ww = wid + 1; ww < 4; ++ww) above += s_wtot[ww];
#pragma unroll
    for (int j = 0; j < 8; ++j) {
      int suf = sl[j] + above;           // count with bin >= (t*8+j)
      if (suf >= Kr && suf - hl[j] < Kr) {
        s_piv[0] = t * 8 + j;
        s_piv[1] = suf - hl[j];          // count strictly greater
      }
    }
    __syncthreads();
    prefix |= ((unsigned)s_piv[0]) << shift;
    pmask |= bmask << shift;
    Kr -= s_piv[1];
    __syncthreads();
  }
  unsigned T = prefix;  // exact rank-TOPK |score| bit pattern

  // ---- compaction: all key>T, plus lowest-index ties at key==T ----
  if (t < 2) s_cnt[t] = 0;
  __syncthreads();
#pragma unroll
  for (int e = 0; e < 16; ++e) {
    int idx4 = (e >> 2) * 256 + t;
    int m = (idx4 >> 4) * 64 + (idx4 & 15) * 4 + (e & 3);  // global col
    if (key[e] > T) {
      int p = atomicAdd(&s_cnt[0], 1);
      s_selidx[p] = m;
      s_selval[p] = v[e];
    } else if (key[e] == T) {
      int p = atomicAdd(&s_cnt[1], 1);
      if (p < 64) { s_tiei[p] = m; s_tiev[p] = v[e]; }
    }
  }
  __syncthreads();
  int cnt_gt = s_cnt[0];
  int need = TOPK - cnt_gt;  // ties to take, lowest index first
  if (wid == 0) {
    int ce = min(s_cnt[1], 64);
    int cand = (lane < ce) ? s_tiei[lane] : 0x7fffffff;
    float cval = (lane < ce) ? s_tiev[lane] : 0.0f;
    for (int i = 0; i < need; ++i) {
      int mi = cand;
#pragma unroll
      for (int o = 32; o > 0; o >>= 1) mi = min(mi, __shfl_xor(mi, o));
      if (cand == mi) {
        s_selidx[cnt_gt + i] = cand;
        s_selval[cnt_gt + i] = cval;
        cand = 0x7fffffff;
      }
    }
    // ---- signed softmax over the selected 32 (one wave, width-32) ----
    float sv = (lane < TOPK) ? s_selval[lane] : 0.0f;
    float aa = fabsf(sv);
    float mx = aa;
#pragma unroll
    for (int o = 16; o > 0; o >>= 1) mx = fmaxf(mx, __shfl_xor(mx, o, 32));
    float e2 = expf(aa - mx);
    float sum = e2;
#pragma unroll
    for (int o = 16; o > 0; o >>= 1) sum += __shfl_xor(sum, o, 32);
    if (lane < TOPK) {
      float sgn = (sv > 0.f) ? 1.f : ((sv < 0.f) ? -1.f : 0.f);
      s_w[lane] = sgn * e2 / sum;
    }
  }
  __syncthreads();

  // ---- aggregate + residual + unit-normalize; replicate across batch ----
  float base = val0[n * DIM + t];
  float msg = 0.f;
#pragma unroll
  for (int kk = 0; kk < TOPK; ++kk)
    msg = fmaf(s_w[kk], val0[(size_t)s_selidx[kk] * DIM + t], msg);
  float o = base + msg;
  float ss = block_sum256(o * o, red);
  o *= 1.0f / fmaxf(sqrtf(ss), 1e-6f);
  for (int b = 0; b < B; ++b) out[((size_t)b * N_SLOTS + n) * DIM + t] = o;
}

extern "C" void kernel_launch(void* const* d_in, const int* in_sizes, int n_in,
                              void* d_out, int out_size, void* d_ws, size_t ws_size,
                              hipStream_t stream) {
  // inputs: 0 batch_size, 1 init_state (unused), 2 init_val, 3 ln_gamma,
  //         4 ln_beta, 5 Wq, 6 Wk
  const float* init_val = (const float*)d_in[2];
  const float* g = (const float*)d_in[3];
  const float* b = (const float*)d_in[4];
  const float* Wq = (const float*)d_in[5];
  const float* Wk = (const float*)d_in[6];
  float* out = (float*)d_out;
  int B = out_size / (N_SLOTS * DIM);  // = 4

  // workspace: val0 4MB | qh/ql/kh/kl 1MB each | S chunk @8MB (tiled layout)
  char* ws = (char*)d_ws;
  float* val0 = (float*)ws;
  __hip_bfloat16* qh = (__hip_bfloat16*)(ws + ((size_t)4 << 20));
  __hip_bfloat16* ql = (__hip_bfloat16*)(ws + ((size_t)5 << 20));
  __hip_bfloat16* kh = (__hip_bfloat16*)(ws + ((size_t)6 << 20));
  __hip_bfloat16* kl = (__hip_bfloat16*)(ws + ((size_t)7 << 20));
  float* S = (float*)(ws + ((size_t)8 << 20));
  size_t rem = ws_size > ((size_t)8 << 20) ? ws_size - ((size_t)8 << 20) : 0;
  int rows_chunk = (int)((rem / ((size_t)N_SLOTS * sizeof(float))) / 64) * 64;
  if (rows_chunk > 1024) rows_chunk = 1024;  // keep S chunk (16MB) cache-resident
  if (rows_chunk < 64) rows_chunk = 64;      // require ~9MB of ws minimum

  hipLaunchKernelGGL(ln_unit_kernel, dim3(N_SLOTS), dim3(DIM), 0, stream,
                     init_val, g, b, val0);
  hipLaunchKernelGGL(qk2_kernel, dim3(N_SLOTS / QR), dim3(256), 0, stream,
                     val0, Wq, Wk, qh, ql, kh, kl);
  for (int start = 0; start < N_SLOTS; start += rows_chunk) {
    int rows = N_SLOTS - start;
    if (rows > rows_chunk) rows = rows_chunk;
    hipLaunchKernelGGL(scores_mfma_kernel, dim3(N_SLOTS / 64, rows / 64),
                       dim3(256), 0, stream, qh, ql, kh, kl, S, start);
    hipLaunchKernelGGL(topk_agg_kernel, dim3(rows), dim3(256), 0, stream,
                       S, val0, out, start, B);
  }
}

// Round 8
// 169.646 us; speedup vs baseline: 1.3902x; 1.1893x over previous
//
#include <hip/hip_runtime.h>
#include <hip/hip_bf16.h>
#include <math.h>

#define N_SLOTS 4096
#define DIM 256
#define HEADS 4
#define RANK 32
#define TOPK 32
#define QK 128  // HEADS*RANK

typedef __attribute__((ext_vector_type(8))) short short8;   // 8 bf16 = 4 VGPR
typedef __attribute__((ext_vector_type(4))) float f32x4;

// ---- block-wide sum over 256 threads (4 waves) ----
__device__ __forceinline__ float block_sum256(float v, float* red) {
#pragma unroll
  for (int o = 32; o > 0; o >>= 1) v += __shfl_xor(v, o);
  int lane = threadIdx.x & 63, wid = threadIdx.x >> 6;
  if (lane == 0) red[wid] = v;
  __syncthreads();
  v = red[0] + red[1] + red[2] + red[3];
  __syncthreads();
  return v;
}

// ---- Kernel A: LayerNorm + unit-normalize rows of init_val -> val0 [N,D] ----
__global__ __launch_bounds__(256) void ln_unit_kernel(
    const float* __restrict__ x, const float* __restrict__ g,
    const float* __restrict__ b, float* __restrict__ val0) {
  __shared__ float red[4];
  int n = blockIdx.x, t = threadIdx.x;
  float v = x[n * DIM + t];
  float mean = block_sum256(v, red) * (1.0f / DIM);
  float d = v - mean;
  float var = block_sum256(d * d, red) * (1.0f / DIM);
  float y = d * rsqrtf(var + 1e-5f) * g[t] + b[t];
  float ss = block_sum256(y * y, red);
  y = y / fmaxf(sqrtf(ss), 1e-6f);
  val0[n * DIM + t] = y;
}

// ---- Kernel B: q/k projections. 256 thr: half 0 computes q (reads Wq only),
//      half 1 computes k (reads Wk only); QR=4 rows/block. bf16 hi/lo split. ----
#define QR 4
__global__ __launch_bounds__(256) void qk2_kernel(
    const float* __restrict__ val0, const float* __restrict__ Wq,
    const float* __restrict__ Wk, __hip_bfloat16* __restrict__ qh,
    __hip_bfloat16* __restrict__ ql, __hip_bfloat16* __restrict__ kh,
    __hip_bfloat16* __restrict__ kl) {
  __shared__ float vrow[QR][DIM];  // 4 KB
  int t = threadIdx.x;
  int n0 = blockIdx.x * QR;
#pragma unroll
  for (int j = 0; j < QR; ++j) {
    int idx = j * 256 + t;
    vrow[idx >> 8][idx & 255] = val0[(size_t)n0 * DIM + idx];
  }
  __syncthreads();
  int half = t >> 7, u = t & 127, h = u >> 5, r = u & 31;
  const float* wp = (half ? Wk : Wq) + (size_t)h * DIM * RANK + r;
  float acc[QR];
#pragma unroll
  for (int i = 0; i < QR; ++i) acc[i] = 0.f;
#pragma unroll 8
  for (int d = 0; d < DIM; ++d) {
    float w = wp[d * RANK];
#pragma unroll
    for (int i = 0; i < QR; ++i) acc[i] = fmaf(vrow[i][d], w, acc[i]);
  }
  __hip_bfloat16* oh = half ? kh : qh;
  __hip_bfloat16* ol = half ? kl : ql;
#pragma unroll
  for (int i = 0; i < QR; ++i) {
    size_t o = (size_t)(n0 + i) * QK + u;
    __hip_bfloat16 hi = __float2bfloat16(acc[i]);
    oh[o] = hi;
    ol[o] = __float2bfloat16(acc[i] - __bfloat162float(hi));
  }
}

// ---- Kernel C: scores via 16x16x32 bf16 MFMA (hh+hl+lh split).
// Block = 128 rows x 64 cols (2 row-subtiles per wave). K-panel staged in
// fragment-ordered XOR-swizzled LDS (32 KB -> 5 blocks/CU). q-frags in
// registers. C-frags stored directly to tiled S:
// tile (ry,cx) 64x64 row-major at ((ry*64)+cx)*4096. ----
__device__ __forceinline__ int swz(int i) { return i ^ ((i >> 4) & 7); }

__global__ __launch_bounds__(256) void scores_mfma_kernel(
    const __hip_bfloat16* __restrict__ qh, const __hip_bfloat16* __restrict__ ql,
    const __hip_bfloat16* __restrict__ kh, const __hip_bfloat16* __restrict__ kl,
    float* __restrict__ S, int row0) {
  __shared__ short8 kfrag[2048];  // [hl][kc][c][lane] 32 KB, swizzled
  int tid = threadIdx.x;
  int w = tid >> 6, l = tid & 63;
  int r = l & 15, g = l >> 4;
  int bcol = blockIdx.x * 64;
  int rowbase = row0 + blockIdx.y * 128;

  // q fragments for both row-subtiles -> registers (16 x 16B loads)
  short8 ah0[4], al0[4], ah1[4], al1[4];
  {
    int arow0 = rowbase + w * 16 + r;
    int arow1 = arow0 + 64;
    const __hip_bfloat16* p0h = qh + (size_t)arow0 * QK + g * 8;
    const __hip_bfloat16* p0l = ql + (size_t)arow0 * QK + g * 8;
    const __hip_bfloat16* p1h = qh + (size_t)arow1 * QK + g * 8;
    const __hip_bfloat16* p1l = ql + (size_t)arow1 * QK + g * 8;
#pragma unroll
    for (int kc = 0; kc < 4; ++kc) {
      ah0[kc] = *(const short8*)(p0h + kc * 32);
      al0[kc] = *(const short8*)(p0l + kc * 32);
      ah1[kc] = *(const short8*)(p1h + kc * 32);
      al1[kc] = *(const short8*)(p1l + kc * 32);
    }
  }

  // stage k panel (rows bcol..bcol+63) into fragment-ordered LDS
#pragma unroll
  for (int p = 0; p < 4; ++p) {
    int ci = p * 256 + tid;  // 0..1023 (16B chunks)
    int row = ci >> 4, j = ci & 15;
    int fi = ((j >> 2) << 8) + ((row >> 4) << 6) + ((j & 3) << 4) + (row & 15);
    kfrag[swz(fi)] = *(const short8*)(kh + (size_t)(bcol + row) * QK + j * 8);
    kfrag[swz(1024 + fi)] = *(const short8*)(kl + (size_t)(bcol + row) * QK + j * 8);
  }
  __syncthreads();

  f32x4 acc0[4], acc1[4];
#pragma unroll
  for (int c = 0; c < 4; ++c) {
    acc0[c] = (f32x4){0.f, 0.f, 0.f, 0.f};
    acc1[c] = (f32x4){0.f, 0.f, 0.f, 0.f};
  }
#pragma unroll
  for (int c = 0; c < 4; ++c) {
#pragma unroll
    for (int kc = 0; kc < 4; ++kc) {
      short8 bh = kfrag[swz(kc * 256 + c * 64 + l)];
      short8 bl = kfrag[swz(1024 + kc * 256 + c * 64 + l)];
      acc0[c] = __builtin_amdgcn_mfma_f32_16x16x32_bf16(ah0[kc], bh, acc0[c], 0, 0, 0);
      acc0[c] = __builtin_amdgcn_mfma_f32_16x16x32_bf16(ah0[kc], bl, acc0[c], 0, 0, 0);
      acc0[c] = __builtin_amdgcn_mfma_f32_16x16x32_bf16(al0[kc], bh, acc0[c], 0, 0, 0);
      acc1[c] = __builtin_amdgcn_mfma_f32_16x16x32_bf16(ah1[kc], bh, acc1[c], 0, 0, 0);
      acc1[c] = __builtin_amdgcn_mfma_f32_16x16x32_bf16(ah1[kc], bl, acc1[c], 0, 0, 0);
      acc1[c] = __builtin_amdgcn_mfma_f32_16x16x32_bf16(al1[kc], bh, acc1[c], 0, 0, 0);
    }
  }
  // direct store of C-frags (col=r, row=g*4+reg) into tiled S
  int ry0 = blockIdx.y * 2;  // chunk-local row-tile index
  int trow = w * 16 + g * 4;
  float* St0 = S + ((size_t)ry0 * 64 + blockIdx.x) * 4096;
  float* St1 = S + ((size_t)(ry0 + 1) * 64 + blockIdx.x) * 4096;
#pragma unroll
  for (int c = 0; c < 4; ++c)
#pragma unroll
    for (int reg = 0; reg < 4; ++reg) {
      St0[(trow + reg) * 64 + c * 16 + r] = acc0[c][reg];
      St1[(trow + reg) * 64 + c * 16 + r] = acc1[c][reg];
    }
}

// ---- Kernel D: per-row exact top-32 via 3-round radix select (11/11/10
//      bits, 4-way wave-privatized 2048-bin histograms), signed softmax,
//      gather-aggregate, unit-normalize. Reads tiled S. ----
__global__ __launch_bounds__(256) void topk_agg_kernel(
    const float* __restrict__ S, const float* __restrict__ val0,
    float* __restrict__ out, int row0, int B) {
  __shared__ int hist[4 * 2048];  // 32 KB, copy per wave
  __shared__ int s_wtot[4];
  __shared__ int s_piv[2];
  __shared__ int s_selidx[TOPK];
  __shared__ float s_selval[TOPK];
  __shared__ int s_tiei[64];
  __shared__ float s_tiev[64];
  __shared__ int s_cnt[2];
  __shared__ float s_w[TOPK];
  __shared__ float red[4];

  int t = threadIdx.x, lane = t & 63, wid = t >> 6;
  int n = row0 + blockIdx.x;
  int rt = blockIdx.x >> 6, rl = blockIdx.x & 63;
  const float* Sbase = S + (size_t)rt * 64 * N_SLOTS + (size_t)rl * 64;

  float v[16];
  unsigned key[16];
#pragma unroll
  for (int it = 0; it < 4; ++it) {
    int idx4 = it * 256 + t;
    int ct = idx4 >> 4, f4 = idx4 & 15;
    float4 f = *(const float4*)(Sbase + (size_t)ct * 4096 + f4 * 4);
    v[it * 4 + 0] = f.x; v[it * 4 + 1] = f.y;
    v[it * 4 + 2] = f.z; v[it * 4 + 3] = f.w;
  }
#pragma unroll
  for (int e = 0; e < 16; ++e) key[e] = __float_as_uint(fabsf(v[e]));

  // ---- radix select: exact threshold key T of rank TOPK ----
  unsigned prefix = 0u, pmask = 0u;
  int Kr = TOPK;
  const int SH[3] = {21, 10, 0};
  const unsigned BM[3] = {2047u, 2047u, 1023u};
#pragma unroll
  for (int rnd = 0; rnd < 3; ++rnd) {
    int shift = SH[rnd];
    unsigned bmask = BM[rnd];
#pragma unroll
    for (int cp = 0; cp < 4; ++cp) {
      *(int4*)&hist[cp * 2048 + t * 8] = (int4){0, 0, 0, 0};
      *(int4*)&hist[cp * 2048 + t * 8 + 4] = (int4){0, 0, 0, 0};
    }
    __syncthreads();
#pragma unroll
    for (int e = 0; e < 16; ++e)
      if ((key[e] & pmask) == prefix)
        atomicAdd(&hist[wid * 2048 + ((key[e] >> shift) & bmask)], 1);
    __syncthreads();
    int hl[8], sl[8];
    {
      int4 a0 = *(const int4*)&hist[0 * 2048 + t * 8];
      int4 a1 = *(const int4*)&hist[1 * 2048 + t * 8];
      int4 a2 = *(const int4*)&hist[2 * 2048 + t * 8];
      int4 a3 = *(const int4*)&hist[3 * 2048 + t * 8];
      int4 b0 = *(const int4*)&hist[0 * 2048 + t * 8 + 4];
      int4 b1 = *(const int4*)&hist[1 * 2048 + t * 8 + 4];
      int4 b2 = *(const int4*)&hist[2 * 2048 + t * 8 + 4];
      int4 b3 = *(const int4*)&hist[3 * 2048 + t * 8 + 4];
      hl[0] = a0.x + a1.x + a2.x + a3.x; hl[1] = a0.y + a1.y + a2.y + a3.y;
      hl[2] = a0.z + a1.z + a2.z + a3.z; hl[3] = a0.w + a1.w + a2.w + a3.w;
      hl[4] = b0.x + b1.x + b2.x + b3.x; hl[5] = b0.y + b1.y + b2.y + b3.y;
      hl[6] = b0.z + b1.z + b2.z + b3.z; hl[7] = b0.w + b1.w + b2.w + b3.w;
    }
    int run = 0;
#pragma unroll
    for (int j = 7; j >= 0; --j) { run += hl[j]; sl[j] = run; }
    int ws = run;
#pragma unroll
    for (int o = 1; o < 64; o <<= 1) {
      int tmp = __shfl_down(ws, o);
      if (lane + o < 64) ws += tmp;
    }
    if (lane == 0) s_wtot[wid] = ws;
    __syncthreads();
    int above = ws - run;
    for (int ww = wid + 1; ww < 4; ++ww) above += s_wtot[ww];
#pragma unroll
    for (int j = 0; j < 8; ++j) {
      int suf = sl[j] + above;           // count with bin >= (t*8+j)
      if (suf >= Kr && suf - hl[j] < Kr) {
        s_piv[0] = t * 8 + j;
        s_piv[1] = suf - hl[j];          // count strictly greater
      }
    }
    __syncthreads();
    prefix |= ((unsigned)s_piv[0]) << shift;
    pmask |= bmask << shift;
    Kr -= s_piv[1];
    __syncthreads();
  }
  unsigned T = prefix;  // exact rank-TOPK |score| bit pattern

  // ---- compaction: all key>T, plus lowest-index ties at key==T ----
  if (t < 2) s_cnt[t] = 0;
  __syncthreads();
#pragma unroll
  for (int e = 0; e < 16; ++e) {
    int idx4 = (e >> 2) * 256 + t;
    int m = (idx4 >> 4) * 64 + (idx4 & 15) * 4 + (e & 3);  // global col
    if (key[e] > T) {
      int p = atomicAdd(&s_cnt[0], 1);
      s_selidx[p] = m;
      s_selval[p] = v[e];
    } else if (key[e] == T) {
      int p = atomicAdd(&s_cnt[1], 1);
      if (p < 64) { s_tiei[p] = m; s_tiev[p] = v[e]; }
    }
  }
  __syncthreads();
  int cnt_gt = s_cnt[0];
  int need = TOPK - cnt_gt;  // ties to take, lowest index first
  if (wid == 0) {
    int ce = min(s_cnt[1], 64);
    int cand = (lane < ce) ? s_tiei[lane] : 0x7fffffff;
    float cval = (lane < ce) ? s_tiev[lane] : 0.0f;
    for (int i = 0; i < need; ++i) {
      int mi = cand;
#pragma unroll
      for (int o = 32; o > 0; o >>= 1) mi = min(mi, __shfl_xor(mi, o));
      if (cand == mi) {
        s_selidx[cnt_gt + i] = cand;
        s_selval[cnt_gt + i] = cval;
        cand = 0x7fffffff;
      }
    }
    // ---- signed softmax over the selected 32 (one wave, width-32) ----
    float sv = (lane < TOPK) ? s_selval[lane] : 0.0f;
    float aa = fabsf(sv);
    float mx = aa;
#pragma unroll
    for (int o = 16; o > 0; o >>= 1) mx = fmaxf(mx, __shfl_xor(mx, o, 32));
    float e2 = expf(aa - mx);
    float sum = e2;
#pragma unroll
    for (int o = 16; o > 0; o >>= 1) sum += __shfl_xor(sum, o, 32);
    if (lane < TOPK) {
      float sgn = (sv > 0.f) ? 1.f : ((sv < 0.f) ? -1.f : 0.f);
      s_w[lane] = sgn * e2 / sum;
    }
  }
  __syncthreads();

  // ---- aggregate + residual + unit-normalize; replicate across batch ----
  float base = val0[n * DIM + t];
  float msg = 0.f;
#pragma unroll
  for (int kk = 0; kk < TOPK; ++kk)
    msg = fmaf(s_w[kk], val0[(size_t)s_selidx[kk] * DIM + t], msg);
  float o = base + msg;
  float ss = block_sum256(o * o, red);
  o *= 1.0f / fmaxf(sqrtf(ss), 1e-6f);
  for (int b = 0; b < B; ++b) out[((size_t)b * N_SLOTS + n) * DIM + t] = o;
}

extern "C" void kernel_launch(void* const* d_in, const int* in_sizes, int n_in,
                              void* d_out, int out_size, void* d_ws, size_t ws_size,
                              hipStream_t stream) {
  // inputs: 0 batch_size, 1 init_state (unused), 2 init_val, 3 ln_gamma,
  //         4 ln_beta, 5 Wq, 6 Wk
  const float* init_val = (const float*)d_in[2];
  const float* g = (const float*)d_in[3];
  const float* b = (const float*)d_in[4];
  const float* Wq = (const float*)d_in[5];
  const float* Wk = (const float*)d_in[6];
  float* out = (float*)d_out;
  int B = out_size / (N_SLOTS * DIM);  // = 4

  // workspace: val0 4MB | qh/ql/kh/kl 1MB each | S chunk @8MB (tiled layout)
  char* ws = (char*)d_ws;
  float* val0 = (float*)ws;
  __hip_bfloat16* qh = (__hip_bfloat16*)(ws + ((size_t)4 << 20));
  __hip_bfloat16* ql = (__hip_bfloat16*)(ws + ((size_t)5 << 20));
  __hip_bfloat16* kh = (__hip_bfloat16*)(ws + ((size_t)6 << 20));
  __hip_bfloat16* kl = (__hip_bfloat16*)(ws + ((size_t)7 << 20));
  float* S = (float*)(ws + ((size_t)8 << 20));
  size_t rem = ws_size > ((size_t)8 << 20) ? ws_size - ((size_t)8 << 20) : 0;
  int rows_chunk = (int)((rem / ((size_t)N_SLOTS * sizeof(float))) / 128) * 128;
  if (rows_chunk > N_SLOTS) rows_chunk = N_SLOTS;  // 64MB S: single chunk
  if (rows_chunk < 128) rows_chunk = 128;          // require ~10MB of ws min

  hipLaunchKernelGGL(ln_unit_kernel, dim3(N_SLOTS), dim3(DIM), 0, stream,
                     init_val, g, b, val0);
  hipLaunchKernelGGL(qk2_kernel, dim3(N_SLOTS / QR), dim3(256), 0, stream,
                     val0, Wq, Wk, qh, ql, kh, kl);
  for (int start = 0; start < N_SLOTS; start += rows_chunk) {
    int rows = N_SLOTS - start;
    if (rows > rows_chunk) rows = rows_chunk;
    hipLaunchKernelGGL(scores_mfma_kernel, dim3(N_SLOTS / 64, rows / 128),
                       dim3(256), 0, stream, qh, ql, kh, kl, S, start);
    hipLaunchKernelGGL(topk_agg_kernel, dim3(rows), dim3(256), 0, stream,
                       S, val0, out, start, B);
  }
}